// Round 2
// baseline (817.087 us; speedup 1.0000x reference)
//
#include <hip/hip_runtime.h>

#define KK 49        // 7*7
#define CH 128       // channels
#define NN 256       // tracks N
#define TT 16        // time
#define LROW 132     // padded LDS row (floats)

__global__ __launch_bounds__(256) void corr_kernel(
    const float* __restrict__ fm,      // (T, C, H, W)
    const float* __restrict__ track,   // (KK, N, C)
    const float* __restrict__ coords,  // (T, N, 2)
    float* __restrict__ out,           // (T, N, KK, KK)
    int H, int W, float inv)
{
    __shared__ float feats[KK][LROW];
    __shared__ float trk[KK][LROW];
    __shared__ int   x0s[KK], x1s[KK], y0s[KK], y1s[KK];
    __shared__ float wxs[KK], wys[KK];

    const int blk = blockIdx.x;
    const int t = blk / NN;
    const int n = blk - t * NN;
    const int tid = threadIdx.x;

    // ---- Phase A: per-point bilinear coords/weights (49 threads) ----
    if (tid < KK) {
        const float cx = coords[(t * NN + n) * 2 + 0] * inv;
        const float cy = coords[(t * NN + n) * 2 + 1] * inv;
        const int h = tid / 7;       // x-offset index
        const int w = tid - h * 7;   // y-offset index
        float x = cx + (float)(h - 3);
        float y = cy + (float)(w - 3);
        x = fminf(fmaxf(x, 0.0f), (float)(W - 1));
        y = fminf(fmaxf(y, 0.0f), (float)(H - 1));
        const float x0 = floorf(x);
        const float y0 = floorf(y);
        wxs[tid] = x - x0;
        wys[tid] = y - y0;
        const int x0i = (int)x0;
        const int y0i = (int)y0;
        x0s[tid] = x0i;
        y0s[tid] = y0i;
        x1s[tid] = min(x0i + 1, W - 1);
        y1s[tid] = min(y0i + 1, H - 1);
    }

    // ---- stage track slice: trk[ij][c] = track[ij, n, c] (coalesced) ----
    {
        const float* tp = track + (size_t)n * CH;
        for (int idx = tid; idx < KK * CH; idx += 256) {
            const int ij = idx >> 7;        // /128
            const int c  = idx & 127;
            trk[ij][c] = tp[(size_t)ij * NN * CH + c];
        }
    }
    __syncthreads();

    // ---- Phase B: bilinear-sample feats[p][c] ----
    {
        const float* fmt = fm + (size_t)t * CH * H * W;
        for (int idx = tid; idx < KK * CH; idx += 256) {
            const int p = idx % KK;
            const int c = idx / KK;
            const int x0 = x0s[p], x1 = x1s[p];
            const int y0 = y0s[p], y1 = y1s[p];
            const float wx = wxs[p], wy = wys[p];
            const float* base = fmt + (size_t)c * H * W;
            const float v00 = base[y0 * W + x0];
            const float v01 = base[y0 * W + x1];
            const float v10 = base[y1 * W + x0];
            const float v11 = base[y1 * W + x1];
            feats[p][c] = v00 * (1.0f - wy) * (1.0f - wx)
                        + v01 * (1.0f - wy) * wx
                        + v10 * wy * (1.0f - wx)
                        + v11 * wy * wx;
        }
    }
    __syncthreads();

    // ---- Phase C: 49x49 output, 4x4 register tile per thread, stride-16 ----
    const int tx = tid & 15;   // ij base
    const int ty = tid >> 4;   // hw base
    int hwr[4], ijs[4];
    #pragma unroll
    for (int r = 0; r < 4; ++r) hwr[r] = min(ty + 16 * r, KK - 1);
    #pragma unroll
    for (int s = 0; s < 4; ++s) ijs[s] = min(tx + 16 * s, KK - 1);

    float acc[4][4];
    #pragma unroll
    for (int r = 0; r < 4; ++r)
        #pragma unroll
        for (int s = 0; s < 4; ++s) acc[r][s] = 0.0f;

    for (int c = 0; c < CH; c += 4) {
        float4 a[4], b[4];
        #pragma unroll
        for (int r = 0; r < 4; ++r) a[r] = *(const float4*)&feats[hwr[r]][c];
        #pragma unroll
        for (int s = 0; s < 4; ++s) b[s] = *(const float4*)&trk[ijs[s]][c];
        #pragma unroll
        for (int r = 0; r < 4; ++r)
            #pragma unroll
            for (int s = 0; s < 4; ++s)
                acc[r][s] += a[r].x * b[s].x + a[r].y * b[s].y
                           + a[r].z * b[s].z + a[r].w * b[s].w;
    }

    float* op = out + (size_t)(t * NN + n) * KK * KK;
    #pragma unroll
    for (int r = 0; r < 4; ++r) {
        const int hw = ty + 16 * r;
        if (hw >= KK) break;
        #pragma unroll
        for (int s = 0; s < 4; ++s) {
            const int ij = tx + 16 * s;
            if (ij < KK) op[hw * KK + ij] = acc[r][s];
        }
    }
}

extern "C" void kernel_launch(void* const* d_in, const int* in_sizes, int n_in,
                              void* d_out, int out_size, void* d_ws, size_t ws_size,
                              hipStream_t stream) {
    // setup_inputs() dict order (interleaved!): fmaps0, track0, fmaps1, track1,
    // fmaps2, track2, fmaps3, track3, coords
    const float* coords = (const float*)d_in[8];
    float* out = (float*)d_out;
    for (int lvl = 0; lvl < 4; ++lvl) {
        const float* fm = (const float*)d_in[2 * lvl];
        const float* tr = (const float*)d_in[2 * lvl + 1];
        const int H = 96 >> lvl;
        const int W = 128 >> lvl;
        const float inv = 1.0f / (float)(1 << lvl);
        float* outl = out + (size_t)lvl * TT * NN * KK * KK;
        hipLaunchKernelGGL(corr_kernel, dim3(TT * NN), dim3(256), 0, stream,
                           fm, tr, coords, outl, H, W, inv);
    }
}

// Round 3
// 482.913 us; speedup vs baseline: 1.6920x; 1.6920x over previous
//
#include <hip/hip_runtime.h>

#define KK 49        // 7*7
#define CH 128       // channels
#define NN 256       // tracks N
#define TT 16        // time

typedef __attribute__((ext_vector_type(8))) short bf16x8;
typedef __attribute__((ext_vector_type(4))) float f32x4;

__device__ __forceinline__ unsigned int f2bf(float f) {
    unsigned int u = __float_as_uint(f);
    return (u + 0x7fffu + ((u >> 16) & 1u)) >> 16;   // RNE fp32->bf16
}

// One block per (level via grid.y, t, n). D-trick: D[g][ij] = fm[grid pixel g] . track[ij],
// g over the 8x8 integer pixel grid covering all bilinear corners of the 7x7 sample window
// (exact: cx+dx is exact in f32 for these ranges, so floor(cx+dx)=floor(cx)+dx; clipped
// points have zero weight toward the out-of-range corner). Then out = bilinear over 4 D rows.
__global__ __launch_bounds__(256, 4) void corr_mfma_kernel(
    const float* __restrict__ fm0, const float* __restrict__ tk0,
    const float* __restrict__ fm1, const float* __restrict__ tk1,
    const float* __restrict__ fm2, const float* __restrict__ tk2,
    const float* __restrict__ fm3, const float* __restrict__ tk3,
    const float* __restrict__ coords, float* __restrict__ out)
{
    const int lvl = blockIdx.y;
    const float* fm  = lvl == 0 ? fm0 : lvl == 1 ? fm1 : lvl == 2 ? fm2 : fm3;
    const float* trk = lvl == 0 ? tk0 : lvl == 1 ? tk1 : lvl == 2 ? tk2 : tk3;
    const int H = 96 >> lvl, W = 128 >> lvl;
    const float inv = 1.0f / (float)(1 << lvl);

    // P: bf16 [64 g][136 pitch]  (17408 B)  -> reused as D: f32 [64 g][68 pitch]
    __shared__ unsigned int smemPD[64 * 68];
    __shared__ unsigned short Tr[64][136];   // bf16 track [ij][c], rows 49..63 unused
    __shared__ int   pxs[8], pys[8];         // clamped grid pixel coords
    __shared__ int   ixs[KK], iys[KK];       // per-point grid indices (0..6)
    __shared__ float wxs[KK], wys[KK];       // bilinear weights

    const int tid  = threadIdx.x;
    const int wave = tid >> 6;
    const int lane = tid & 63;
    const int t = blockIdx.x >> 8;
    const int n = blockIdx.x & 255;

    // ---- Phase A: grid + per-point indices/weights ----
    if (tid < KK) {
        const float cx = coords[(t * NN + n) * 2 + 0] * inv;
        const float cy = coords[(t * NN + n) * 2 + 1] * inv;
        const int gx0 = (int)floorf(cx) - 3;
        const int gy0 = (int)floorf(cy) - 3;
        if (tid < 8) {
            pxs[tid] = min(max(gx0 + tid, 0), W - 1);
            pys[tid] = min(max(gy0 + tid, 0), H - 1);
        }
        const int h = tid / 7;            // x-offset index
        const int w = tid - h * 7;        // y-offset index
        float x = fminf(fmaxf(cx + (float)(h - 3), 0.0f), (float)(W - 1));
        float y = fminf(fmaxf(cy + (float)(w - 3), 0.0f), (float)(H - 1));
        const float x0 = floorf(x), y0 = floorf(y);
        wxs[tid] = x - x0;
        wys[tid] = y - y0;
        ixs[tid] = min(max((int)x0 - gx0, 0), 6);
        iys[tid] = min(max((int)y0 - gy0, 0), 6);
    }

    // ---- Track staging: Tr[ij][c] = bf16(trk[ij, n, c]), 2 channels/thread ----
    {
        const float* tp = trk + (size_t)n * CH;
        unsigned int* TrU = (unsigned int*)&Tr[0][0];   // pitch 68 uints
        for (int idx = tid; idx < KK * 64; idx += 256) {
            const int ij = idx >> 6;
            const int cp = idx & 63;
            const float2 v = *(const float2*)(tp + (size_t)ij * (NN * CH) + 2 * cp);
            TrU[ij * 68 + cp] = f2bf(v.x) | (f2bf(v.y) << 16);
        }
    }
    __syncthreads();

    // ---- P staging: P[g][c] = bf16(fm[t, c, py[g/8], px[g%8]]) ----
    {
        const int HW = H * W;
        const float* base = fm + (size_t)t * CH * HW + (pys[lane >> 3] * W + pxs[lane & 7]);
        for (int j = wave; j < 64; j += 4) {            // j = channel pair
            const float a0 = base[(size_t)(2 * j) * HW];
            const float a1 = base[(size_t)(2 * j + 1) * HW];
            smemPD[lane * 68 + j] = f2bf(a0) | (f2bf(a1) << 16);
        }
    }
    __syncthreads();

    // ---- GEMM: D[64 g][64 ij] = P(64x128) x Tr^T(128x64), per-wave 16-col strip ----
    f32x4 acc[4];
    #pragma unroll
    for (int m = 0; m < 4; ++m) acc[m] = (f32x4){0.f, 0.f, 0.f, 0.f};
    {
        const unsigned short* P = (const unsigned short*)smemPD;  // pitch 136
        const int mr = lane & 15;
        const int q  = lane >> 4;
        #pragma unroll
        for (int ks = 0; ks < 4; ++ks) {
            const int kof = ks * 32 + q * 8;
            const bf16x8 b = *(const bf16x8*)&Tr[wave * 16 + mr][kof];
            #pragma unroll
            for (int m = 0; m < 4; ++m) {
                const bf16x8 a = *(const bf16x8*)&P[(m * 16 + mr) * 136 + kof];
                acc[m] = __builtin_amdgcn_mfma_f32_16x16x32_bf16(a, b, acc[m], 0, 0, 0);
            }
        }
    }
    __syncthreads();   // all waves done reading P before overwriting with D

    // ---- Spill D (C/D layout: col=lane&15, row=quad*4+reg) ----
    {
        float* D = (float*)smemPD;   // pitch 68
        const int col = wave * 16 + (lane & 15);
        const int q = lane >> 4;
        #pragma unroll
        for (int m = 0; m < 4; ++m) {
            #pragma unroll
            for (int r = 0; r < 4; ++r) {
                D[(m * 16 + q * 4 + r) * 68 + col] = acc[m][r];
            }
        }
    }
    __syncthreads();

    // ---- Interp + store: out[p][ij] = bilinear of 4 D rows ----
    {
        const float* D = (const float*)smemPD;
        float* op = out + (((size_t)lvl * TT + t) * NN + n) * (KK * KK);
        for (int idx = tid; idx < KK * KK; idx += 256) {
            const int p  = idx / KK;
            const int ij = idx - p * KK;
            const float wx = wxs[p], wy = wys[p];
            const float* d0 = &D[(iys[p] * 8 + ixs[p]) * 68 + ij];
            const float v00 = d0[0];
            const float v01 = d0[68];          // gx+1
            const float v10 = d0[8 * 68];      // gy+1
            const float v11 = d0[9 * 68];
            op[idx] = v00 * (1.f - wy) * (1.f - wx) + v01 * (1.f - wy) * wx
                    + v10 * wy * (1.f - wx)       + v11 * wy * wx;
        }
    }
}

extern "C" void kernel_launch(void* const* d_in, const int* in_sizes, int n_in,
                              void* d_out, int out_size, void* d_ws, size_t ws_size,
                              hipStream_t stream) {
    // setup_inputs() dict order (interleaved): fmaps0, track0, fmaps1, track1,
    // fmaps2, track2, fmaps3, track3, coords
    hipLaunchKernelGGL(corr_mfma_kernel, dim3(TT * NN, 4), dim3(256), 0, stream,
                       (const float*)d_in[0], (const float*)d_in[1],
                       (const float*)d_in[2], (const float*)d_in[3],
                       (const float*)d_in[4], (const float*)d_in[5],
                       (const float*)d_in[6], (const float*)d_in[7],
                       (const float*)d_in[8], (float*)d_out);
}